// Round 8
// baseline (113.631 us; speedup 1.0000x reference)
//
#include <hip/hip_runtime.h>
#include <stdint.h>

#define UNITS 4096
#define TPB   256
#define EPT   16
#define RPB   8       // rows per block (banded); 16384 -> 2048 blocks = 8/CU
#define CAP   320     // window count ~242 +- 15; cap = +5.2 sigma (fallback catches misses)
#define NSLOT 5       // CAP/64
#define LOF   0.44f   // theta ~= 0.5244 +- 0.0206 ; [LO,HI) = +-4 sigma
#define HIF   0.61f
#define SELBITS 22    // bits(HIF)-bits(LOF) = 0x3AE148 < 2^22

// LDS-only barrier (no vmcnt drain -> DMA prefetch stays in flight)
__device__ __forceinline__ void lds_barrier() {
    asm volatile("s_waitcnt lgkmcnt(0)" ::: "memory");
    __builtin_amdgcn_s_barrier();
}
__device__ __forceinline__ uint32_t flipu(uint32_t b) {
    return b ^ (uint32_t)(((int32_t)b >> 31) | (int32_t)0x80000000);
}
// popcount of mask bits strictly below this lane
__device__ __forceinline__ uint32_t mbcnt64(uint64_t m) {
    return __builtin_amdgcn_mbcnt_hi((uint32_t)(m >> 32),
           __builtin_amdgcn_mbcnt_lo((uint32_t)m, 0u));
}
// async global->LDS, 16B/lane; LDS dst = wave-uniform base + lane*16
__device__ __forceinline__ void dma16(const float* g, float* l) {
    __builtin_amdgcn_global_load_lds(
        (const __attribute__((address_space(1))) void*)g,
        (__attribute__((address_space(3))) void*)l, 16, 0, 0);
}

__global__ __launch_bounds__(TPB, 8) void ksparse_select_kernel(
        const float* __restrict__ X, float* __restrict__ out,
        int kidx, int nblocks, int rpb) {
    __shared__ float    buf[UNITS];   // 16 KiB DMA target (next row)
    __shared__ uint32_t list[CAP];    // 1.25 KiB window list
    __shared__ uint32_t cnt;
    __shared__ uint32_t wnb[4];       // per-wave count below LO
    __shared__ uint32_t thu_s;        // broadcast theta bits
    __shared__ uint32_t fbc[4];       // fallback per-wave counts

    const int t    = threadIdx.x;
    const int w    = t >> 6;
    const int lane = t & 63;

    // row 0 straight to registers
    float f[EPT];
    {
        const float4* Xv = reinterpret_cast<const float4*>(X + (size_t)blockIdx.x * UNITS);
#pragma unroll
        for (int j = 0; j < 4; ++j) {
            float4 v = Xv[j * 256 + t];
            f[4*j] = v.x; f[4*j+1] = v.y; f[4*j+2] = v.z; f[4*j+3] = v.w;
        }
    }
    // DMA prefetch row 1 (no dst registers -> regalloc-immune)
    if (rpb > 1) {
        const float* g = X + ((size_t)nblocks + blockIdx.x) * UNITS;
        const int base = (w << 6);
#pragma unroll
        for (int j = 0; j < 4; ++j) dma16(g + 4*(j*256+t), buf + 4*(j*256+base));
    }
    if (t == 0) cnt = 0u;

    const uint32_t k   = (uint32_t)kidx;
    const uint32_t LOu = __float_as_uint(LOF);

#pragma unroll 1
    for (int r = 0;; ++r) {
        lds_barrier();   // (a) cnt reset visible; prior row's list/LDS reads done

        // fused window pass: ballots once, masks kept (SGPR-resident), running prefix
        uint64_t mwin[EPT];
        uint32_t nbw = 0, wtot = 0;
#pragma unroll
        for (int e = 0; e < EPT; ++e) {
            const uint64_t mlo = __ballot(f[e] < LOF);
            const uint64_t mhi = __ballot(f[e] < HIF);
            mwin[e] = mhi & ~mlo;
            nbw  += (uint32_t)__popcll(mlo);
            wtot += (uint32_t)__popcll(mwin[e]);
        }
        if (lane == 0) wnb[w] = nbw;

        // reserve list space (one atomic per wave), ballot-ranked scatter
        uint32_t base2 = 0;
        if (lane == 0) base2 = atomicAdd(&cnt, wtot);
        base2 = __shfl(base2, 0);
        uint32_t pfx = 0;
#pragma unroll
        for (int e = 0; e < EPT; ++e) {
            if (mwin[e] & (1ull << lane)) {
                const uint32_t idx = base2 + pfx + mbcnt64(mwin[e]);
                if (idx < CAP) list[idx] = __float_as_uint(f[e]);  // positive: order-preserving bits
            }
            pfx += (uint32_t)__popcll(mwin[e]);
        }

        lds_barrier();   // (b) list + wnb + cnt visible

        const uint32_t c  = cnt;
        const uint32_t cb = wnb[0] + wnb[1] + wnb[2] + wnb[3];
        const bool fast = (cb <= k) && (k < cb + c) && (c <= CAP);  // block-uniform

        float4* Ov = reinterpret_cast<float4*>(out + ((size_t)r * nblocks + blockIdx.x) * UNITS);

        if (fast) {
            if (w == 0) {   // single-wave select (others wait at (c))
                const uint32_t rr = k - cb;   // rank of theta within the list
                uint32_t sv[NSLOT];
#pragma unroll
                for (int i = 0; i < NSLOT; ++i) {
                    const uint32_t ix = (uint32_t)lane + 64u * i;
                    sv[i] = (ix < c) ? (list[ix] - LOu) : 0xFFFFFFFFu;
                }
                uint32_t p = 0;
#pragma unroll
                for (int b = SELBITS - 1; b >= 0; --b) {
                    const uint32_t mid = p | (1u << b);
                    uint32_t cm = 0;
#pragma unroll
                    for (int i = 0; i < NSLOT; ++i)
                        cm += (uint32_t)__popcll(__ballot(sv[i] < mid));
                    if (cm <= rr) p = mid;   // wave-uniform
                }
                if (lane == 0) thu_s = LOu + p;  // exact bits of theta
            }
            lds_barrier();  // (c) thu_s visible
            const float th = __uint_as_float(thu_s);
            if (t == 0) cnt = 0u;   // reset for next row (everyone read c already)
#pragma unroll
            for (int j = 0; j < 4; ++j) {
                float4 o;
                o.x = (f[4*j]   >= th) ? f[4*j]   : 0.0f;
                o.y = (f[4*j+1] >= th) ? f[4*j+1] : 0.0f;
                o.z = (f[4*j+2] >= th) ? f[4*j+2] : 0.0f;
                o.w = (f[4*j+3] >= th) ? f[4*j+3] : 0.0f;
                Ov[j*256+t] = o;
            }
        } else {
            // exact block-wide fallback (expected <1 row/dataset): 32-bit bit-search
            uint32_t p = 0;
#pragma unroll 1
            for (int b = 31; b >= 0; --b) {
                const uint32_t mid = p | (1u << b);
                uint32_t cw = 0;
#pragma unroll
                for (int e = 0; e < EPT; ++e)
                    cw += (uint32_t)__popcll(__ballot(flipu(__float_as_uint(f[e])) < mid));
                if (lane == 0) fbc[w] = cw;
                lds_barrier();
                const uint32_t cm = fbc[0] + fbc[1] + fbc[2] + fbc[3];
                if (cm <= k) p = mid;   // block-uniform
                lds_barrier();          // fbc consumed before next overwrite
            }
            if (t == 0) cnt = 0u;
#pragma unroll
            for (int j = 0; j < 4; ++j) {
                float4 o;
                o.x = (flipu(__float_as_uint(f[4*j]))   >= p) ? f[4*j]   : 0.0f;
                o.y = (flipu(__float_as_uint(f[4*j+1])) >= p) ? f[4*j+1] : 0.0f;
                o.z = (flipu(__float_as_uint(f[4*j+2])) >= p) ? f[4*j+2] : 0.0f;
                o.w = (flipu(__float_as_uint(f[4*j+3])) >= p) ? f[4*j+3] : 0.0f;
                Ov[j*256+t] = o;
            }
        }

        if (r + 1 >= rpb) break;

        // consume prefetched row r+1: vmcnt retires in order; the 4 newest
        // outstanding VMEM ops are this row's stores, so <=4 => DMAs landed.
        asm volatile("s_waitcnt vmcnt(4)" ::: "memory");
        __builtin_amdgcn_sched_barrier(0);
        {
            const float4* bv = reinterpret_cast<const float4*>(buf);
            float4 v[4];
#pragma unroll
            for (int j = 0; j < 4; ++j) v[j] = bv[j*256+t];       // own lane's bytes
            asm volatile("s_waitcnt lgkmcnt(0)" ::: "memory");    // buf reusable
            __builtin_amdgcn_sched_barrier(0);
            if (r + 2 < rpb) {   // prefetch row r+2 over the freed buffer
                const float* g = X + ((size_t)(r + 2) * nblocks + blockIdx.x) * UNITS;
                const int base = (w << 6);
#pragma unroll
                for (int j = 0; j < 4; ++j) dma16(g + 4*(j*256+t), buf + 4*(j*256+base));
            }
#pragma unroll
            for (int j = 0; j < 4; ++j) {
                f[4*j] = v[j].x; f[4*j+1] = v[j].y; f[4*j+2] = v[j].z; f[4*j+3] = v[j].w;
            }
        }
    }
}

extern "C" void kernel_launch(void* const* d_in, const int* in_sizes, int n_in,
                              void* d_out, int out_size, void* d_ws, size_t ws_size,
                              hipStream_t stream) {
    const float* X = (const float*)d_in[0];
    float* out = (float*)d_out;
    const int rows = in_sizes[0] / UNITS;
    const int kidx = (int)(0.7 * UNITS);  // 2867
    const int rpb = (rows % RPB == 0) ? RPB : 1;
    const int nblocks = rows / rpb;
    ksparse_select_kernel<<<nblocks, TPB, 0, stream>>>(X, out, kidx, nblocks, rpb);
}

// Round 9
// 99.660 us; speedup vs baseline: 1.1402x; 1.1402x over previous
//
#include <hip/hip_runtime.h>
#include <stdint.h>

#define UNITS  4096
#define CAP    320        // window count ~242 +- 15; cap = +5.2 sigma (fallback catches misses)
#define NSLOT  5          // CAP/64
#define LOF    0.44f      // theta ~= 0.5244 +- 0.0206 ; [LO,HI) = +-4 sigma
#define HIF    0.61f
#define SELBITS 22        // bits(0.61f)-bits(0.44f) = 0x3AE148 < 2^22

// LDS-only barrier (no vmcnt drain)
__device__ __forceinline__ void lds_barrier() {
    asm volatile("s_waitcnt lgkmcnt(0)" ::: "memory");
    __builtin_amdgcn_s_barrier();
}
__device__ __forceinline__ uint32_t flipu(uint32_t b) {
    return b ^ (uint32_t)(((int32_t)b >> 31) | (int32_t)0x80000000);
}
// popcount of mask bits strictly below this lane
__device__ __forceinline__ uint32_t mbcnt64(uint64_t m) {
    return __builtin_amdgcn_mbcnt_hi((uint32_t)(m >> 32),
           __builtin_amdgcn_mbcnt_lo((uint32_t)m, 0u));
}

// One block (256 threads) per row — R6 structure.
// Fast path: count-below-LO + compact window [LO,HI) into LDS list (rebased
// 22-bit keys), then all 4 waves redundantly radix-select rank (k - cb) via
// ballots (no barriers), mask-store from registers. Bracket verified per row;
// failures take the exact block-wide 32-bit bit-search fallback.
__global__ __launch_bounds__(256, 8) void ksparse_select_kernel(
        const float* __restrict__ X, float* __restrict__ out, int kidx) {
    __shared__ uint32_t list[CAP];  // 1.25 KiB
    __shared__ uint32_t cnt;
    __shared__ uint32_t wnb[4];     // per-wave count below LO
    __shared__ uint32_t fbc[4];     // fallback per-wave counts

    const int t    = threadIdx.x;
    const int w    = t >> 6;
    const int lane = t & 63;

    if (t == 0) cnt = 0u;

    // load row (coalesced float4)
    float f[16];
    {
        const float4* Xv = reinterpret_cast<const float4*>(X + (size_t)blockIdx.x * UNITS);
#pragma unroll
        for (int j = 0; j < 4; ++j) {
            float4 v = Xv[j * 256 + t];
            f[4*j] = v.x; f[4*j+1] = v.y; f[4*j+2] = v.z; f[4*j+3] = v.w;
        }
    }

    lds_barrier();  // cnt zeroed everywhere

    // pass 1: window ballots once; keep masks (wave-uniform) for the scatter
    uint64_t mwin[16];
    uint32_t nbw = 0, wtot = 0;
#pragma unroll
    for (int e = 0; e < 16; ++e) {
        const uint64_t mlo = __ballot(f[e] < LOF);
        const uint64_t mhi = __ballot(f[e] < HIF);
        mwin[e] = mhi & ~mlo;
        nbw  += (uint32_t)__popcll(mlo);
        wtot += (uint32_t)__popcll(mwin[e]);
    }
    if (lane == 0) wnb[w] = nbw;

    // reserve list space (one atomic per wave), ballot-ranked scatter of
    // REBASED keys (u - LOu < 2^22); no ballots recomputed here
    const uint32_t LOu = __float_as_uint(LOF);
    uint32_t base = 0;
    if (lane == 0) base = atomicAdd(&cnt, wtot);
    base = __shfl(base, 0);
    uint32_t pfx = 0;
#pragma unroll
    for (int e = 0; e < 16; ++e) {
        if (mwin[e] & (1ull << lane)) {
            const uint32_t idx = base + pfx + mbcnt64(mwin[e]);
            if (idx < CAP) list[idx] = __float_as_uint(f[e]) - LOu;
        }
        pfx += (uint32_t)__popcll(mwin[e]);
    }

    lds_barrier();  // list + cnt + wnb visible

    const uint32_t c  = cnt;
    const uint32_t cb = wnb[0] + wnb[1] + wnb[2] + wnb[3];
    const uint32_t k  = (uint32_t)kidx;

    float4* Ov = reinterpret_cast<float4*>(out + (size_t)blockIdx.x * UNITS);

    if (cb <= k && k < cb + c && c <= CAP) {   // block-uniform bracket check
        const uint32_t r = k - cb;             // rank of theta within the list

        // every wave loads the whole list (64-lane distributed), sentinel-padded
        uint32_t sv[NSLOT];
#pragma unroll
        for (int i = 0; i < NSLOT; ++i) {
            const uint32_t ix = (uint32_t)lane + 64u * i;
            sv[i] = (ix < c) ? list[ix] : 0xFFFFFFFFu;
        }

        // MSB-first ballot radix select over 22 rebased bits (wave-local)
        uint32_t p = 0;
#pragma unroll
        for (int b = SELBITS - 1; b >= 0; --b) {
            const uint32_t mid = p | (1u << b);
            uint32_t cm = 0;
#pragma unroll
            for (int i = 0; i < NSLOT; ++i)
                cm += (uint32_t)__popcll(__ballot(sv[i] < mid));
            if (cm <= r) p = mid;   // wave-uniform
        }
        const float th = __uint_as_float(LOu + p);  // exact bits of theta

#pragma unroll
        for (int j = 0; j < 4; ++j) {
            float4 o;
            o.x = (f[4*j]   >= th) ? f[4*j]   : 0.0f;
            o.y = (f[4*j+1] >= th) ? f[4*j+1] : 0.0f;
            o.z = (f[4*j+2] >= th) ? f[4*j+2] : 0.0f;
            o.w = (f[4*j+3] >= th) ? f[4*j+3] : 0.0f;
            Ov[j * 256 + t] = o;
        }
    } else {
        // exact block-wide fallback (~1 row/dataset): 32-bit MSB bit-search
        uint32_t p = 0;
#pragma unroll 1
        for (int b = 31; b >= 0; --b) {
            const uint32_t mid = p | (1u << b);
            uint32_t cw = 0;
#pragma unroll
            for (int e = 0; e < 16; ++e)
                cw += (uint32_t)__popcll(__ballot(flipu(__float_as_uint(f[e])) < mid));
            if (lane == 0) fbc[w] = cw;
            lds_barrier();
            const uint32_t cm = fbc[0] + fbc[1] + fbc[2] + fbc[3];
            if (cm <= k) p = mid;   // block-uniform
            lds_barrier();          // fbc consumed before next overwrite
        }
#pragma unroll
        for (int j = 0; j < 4; ++j) {
            float4 o;
            o.x = (flipu(__float_as_uint(f[4*j]))   >= p) ? f[4*j]   : 0.0f;
            o.y = (flipu(__float_as_uint(f[4*j+1])) >= p) ? f[4*j+1] : 0.0f;
            o.z = (flipu(__float_as_uint(f[4*j+2])) >= p) ? f[4*j+2] : 0.0f;
            o.w = (flipu(__float_as_uint(f[4*j+3])) >= p) ? f[4*j+3] : 0.0f;
            Ov[j * 256 + t] = o;
        }
    }
}

extern "C" void kernel_launch(void* const* d_in, const int* in_sizes, int n_in,
                              void* d_out, int out_size, void* d_ws, size_t ws_size,
                              hipStream_t stream) {
    const float* X = (const float*)d_in[0];
    float* out = (float*)d_out;
    const int rows = in_sizes[0] / UNITS;
    const int kidx = (int)(0.7 * UNITS);  // 2867
    ksparse_select_kernel<<<rows, 256, 0, stream>>>(X, out, kidx);
}